// Round 8
// baseline (97.209 us; speedup 1.0000x reference)
//
#include <hip/hip_runtime.h>

#define N_MENT   10000
#define BATCH    512
#define N_ANTS   50
#define EMB      1024
#define PW_EMB   64
#define IN_F     3136       // 3*EMB + PW_EMB
#define HID      128
#define M_TOT    (BATCH * N_ANTS)   // 25600
#define EPS_VAL  1e-7f
#define SLOPE    0.01f

#define NKT      98         // IN_F/32 k-tiles, permuted: chunk c -> [a,a,b,b,s,s], then pw,pw
#define CONV_BLK 196        // 8 tn * 98 tk * 64 lanes / 256
#define MAIN_BLK (M_TOT / 32)   // 800

using f32x4 = __attribute__((ext_vector_type(4))) float;
using s16x8 = __attribute__((ext_vector_type(8))) short;
using u16x8 = __attribute__((ext_vector_type(8))) unsigned short;

__device__ __forceinline__ unsigned short f2bf(float f) {
  unsigned u = __builtin_bit_cast(unsigned, f);
  u += 0x7FFFu + ((u >> 16) & 1u);   // RNE
  return (unsigned short)(u >> 16);
}

// pack 8 f32 -> 8 bf16 (RNE) via v_cvt_pk_bf16_f32 (bit-equal to f2bf; verified R4-R7)
__device__ __forceinline__ s16x8 pack8(float4 lo, float4 hi) {
  union { s16x8 v; unsigned u[4]; } r;
  asm("v_cvt_pk_bf16_f32 %0, %1, %2" : "=v"(r.u[0]) : "v"(lo.x), "v"(lo.y));
  asm("v_cvt_pk_bf16_f32 %0, %1, %2" : "=v"(r.u[1]) : "v"(lo.z), "v"(lo.w));
  asm("v_cvt_pk_bf16_f32 %0, %1, %2" : "=v"(r.u[2]) : "v"(hi.x), "v"(hi.y));
  asm("v_cvt_pk_bf16_f32 %0, %1, %2" : "=v"(r.u[3]) : "v"(hi.z), "v"(hi.w));
  return r.v;
}

__device__ __forceinline__ float4 fmul4(float4 a, float4 b) {
  return make_float4(a.x * b.x, a.y * b.y, a.z * b.z, a.w * b.w);
}
__device__ __forceinline__ float lky(float h) { return h > 0.f ? h : SLOPE * h; }

// permuted k-tile -> original W1 row base.
//   tk in [0,96): chunk c = tk/6, r = tk%6; region = r>>1 (0=a,1=b,2=sim), ks = r&1
//                 orig = region*1024 + c*64 + ks*32
//   tk 96,97   -> pw rows 3072 + (tk-96)*32
__device__ __forceinline__ int tile_orig_k(int tk) {
  if (tk >= 96) return 3072 + (tk - 96) * 32;
  const int c = tk / 6, r = tk % 6;
  return (r >> 1) * 1024 + c * 64 + (r & 1) * 32;
}

// ---- kernel 0: W1 [3136][128] f32 -> w1f in MFMA fragment-linear order ------
// w1f element index = ((tn*NKT + tk)*64 + lane)*8 + j
//   lane = ln + lg*16 holds W1[k = orig_k(tk) + lg*8 + j][n = tn*16 + ln]
__global__ __launch_bounds__(256) void k_convert(const float* __restrict__ w1,
                                                 unsigned short* __restrict__ w1f) {
  const int id   = blockIdx.x * 256 + threadIdx.x;   // 0..50175
  const int lane = id & 63;
  const int tile = id >> 6;                          // 0..783 = tn*98 + tk
  const int tk   = tile % NKT, tn = tile / NKT;
  const int n    = tn * 16 + (lane & 15);
  const int k    = tile_orig_k(tk) + (lane >> 4) * 8;
  u16x8 o;
  #pragma unroll
  for (int j = 0; j < 8; ++j) o[j] = f2bf(w1[(size_t)(k + j) * HID + n]);
  *(u16x8*)(w1f + (size_t)id * 8) = o;
}

// ---- kernel 1: barrier-free fused GEMM, K=3136, swapped MFMA operands -------
// Wave w of a 32-pair block: m-group mg=w&1 (16 pairs, m=ln), n-half nh=w>>1
// (64 cols, 4 n-tiles). X-fragments built directly in registers from global
// (lane (ln,lg) owns row ln, k-slice lg*8). mfma(W_frag, X_frag) -> C^T:
// lane holds C[m=ln][n = nh*64 + nj*16 + lg*4 + e]. No LDS, no K-loop barriers.
__global__ __launch_bounds__(256) void k_main(
    const float* __restrict__ all_m, const float* __restrict__ men,
    const float* __restrict__ pw, const int* __restrict__ topi,
    const float* __restrict__ rough, const unsigned short* __restrict__ w1f,
    const float* __restrict__ b1, const float* __restrict__ wout,
    const float* __restrict__ bout, float* __restrict__ out) {
  __shared__ float red[64];

  const int t    = threadIdx.x;
  const int lane = t & 63, wid = t >> 6;
  const int ln   = lane & 15, lg = lane >> 4;
  const int mg   = wid & 1, nh = wid >> 1;
  const int m0   = blockIdx.x * 32;

  const int mrow = m0 + mg * 16 + ln;
  const int bb   = mrow / N_ANTS;
  const int bidx = topi[mrow];
  const float* pa = men   + (size_t)bb   * EMB    + lg * 8;
  const float* pb = all_m + (size_t)bidx * EMB    + lg * 8;
  const float* pp = pw    + (size_t)mrow * PW_EMB + lg * 8;

  const unsigned short* wp0 = w1f + (size_t)(nh * 4 + 0) * NKT * 512 + lane * 8;
  const unsigned short* wp1 = w1f + (size_t)(nh * 4 + 1) * NKT * 512 + lane * 8;
  const unsigned short* wp2 = w1f + (size_t)(nh * 4 + 2) * NKT * 512 + lane * 8;
  const unsigned short* wp3 = w1f + (size_t)(nh * 4 + 3) * NKT * 512 + lane * 8;

  f32x4 acc[4] = {};

  // current-chunk raw rows (a: ks0 = ca0/ca1, ks1 = ca2/ca3; b likewise)
  float4 ca0 = ((const float4*)pa)[0],        ca1 = ((const float4*)pa)[1];
  float4 ca2 = ((const float4*)(pa + 32))[0], ca3 = ((const float4*)(pa + 32))[1];
  float4 cb0 = ((const float4*)pb)[0],        cb1 = ((const float4*)pb)[1];
  float4 cb2 = ((const float4*)(pb + 32))[0], cb3 = ((const float4*)(pb + 32))[1];

  for (int c = 0; c < 16; ++c) {
    // depth-1 prefetch of next chunk (pw rows at the end)
    float4 na0, na1, na2, na3, nb0, nb1, nb2, nb3;
    if (c < 15) {
      const float* qa = pa + (c + 1) * 64;
      const float* qb = pb + (c + 1) * 64;
      na0 = ((const float4*)qa)[0];        na1 = ((const float4*)qa)[1];
      na2 = ((const float4*)(qa + 32))[0]; na3 = ((const float4*)(qa + 32))[1];
      nb0 = ((const float4*)qb)[0];        nb1 = ((const float4*)qb)[1];
      nb2 = ((const float4*)(qb + 32))[0]; nb3 = ((const float4*)(qb + 32))[1];
    } else {
      na0 = ((const float4*)pp)[0];        na1 = ((const float4*)pp)[1];
      na2 = ((const float4*)(pp + 32))[0]; na3 = ((const float4*)(pp + 32))[1];
      nb0 = na0; nb1 = na1; nb2 = na2; nb3 = na3;   // unused
    }

    // pack this chunk's 6 X-fragments (a ks0/ks1, b ks0/ks1, sim ks0/ks1)
    s16x8 xf[6];
    xf[0] = pack8(ca0, ca1);
    xf[1] = pack8(ca2, ca3);
    xf[2] = pack8(cb0, cb1);
    xf[3] = pack8(cb2, cb3);
    xf[4] = pack8(fmul4(ca0, cb0), fmul4(ca1, cb1));
    xf[5] = pack8(fmul4(ca2, cb2), fmul4(ca3, cb3));

    #pragma unroll
    for (int j = 0; j < 6; ++j) {
      const size_t off = (size_t)(c * 6 + j) * 512;
      const s16x8 w0 = *(const s16x8*)(wp0 + off);
      const s16x8 w1r = *(const s16x8*)(wp1 + off);
      const s16x8 w2 = *(const s16x8*)(wp2 + off);
      const s16x8 w3 = *(const s16x8*)(wp3 + off);
      acc[0] = __builtin_amdgcn_mfma_f32_16x16x32_bf16(w0,  xf[j], acc[0], 0, 0, 0);
      acc[1] = __builtin_amdgcn_mfma_f32_16x16x32_bf16(w1r, xf[j], acc[1], 0, 0, 0);
      acc[2] = __builtin_amdgcn_mfma_f32_16x16x32_bf16(w2,  xf[j], acc[2], 0, 0, 0);
      acc[3] = __builtin_amdgcn_mfma_f32_16x16x32_bf16(w3,  xf[j], acc[3], 0, 0, 0);
    }
    ca0 = na0; ca1 = na1; ca2 = na2; ca3 = na3;
    cb0 = nb0; cb1 = nb1; cb2 = nb2; cb3 = nb3;
  }

  // pw chunk: values are in ca0..ca3; k-tiles 96,97
  {
    s16x8 xf0 = pack8(ca0, ca1);
    s16x8 xf1 = pack8(ca2, ca3);
    #pragma unroll
    for (int ks = 0; ks < 2; ++ks) {
      const size_t off = (size_t)(96 + ks) * 512;
      const s16x8 w0 = *(const s16x8*)(wp0 + off);
      const s16x8 w1r = *(const s16x8*)(wp1 + off);
      const s16x8 w2 = *(const s16x8*)(wp2 + off);
      const s16x8 w3 = *(const s16x8*)(wp3 + off);
      const s16x8 x = ks ? xf1 : xf0;
      acc[0] = __builtin_amdgcn_mfma_f32_16x16x32_bf16(w0,  x, acc[0], 0, 0, 0);
      acc[1] = __builtin_amdgcn_mfma_f32_16x16x32_bf16(w1r, x, acc[1], 0, 0, 0);
      acc[2] = __builtin_amdgcn_mfma_f32_16x16x32_bf16(w2,  x, acc[2], 0, 0, 0);
      acc[3] = __builtin_amdgcn_mfma_f32_16x16x32_bf16(w3,  x, acc[3], 0, 0, 0);
    }
  }

  // epilogue: lane (ln,lg) holds C[m=ln][n = nh*64 + nj*16 + lg*4 + e]
  const float* b1p = b1   + nh * 64 + lg * 4;
  const float* wop = wout + nh * 64 + lg * 4;
  float ss = 0.f;
  #pragma unroll
  for (int nj = 0; nj < 4; ++nj) {
    const float4 bv = *(const float4*)(b1p + nj * 16);
    const float4 wv = *(const float4*)(wop + nj * 16);
    ss = fmaf(lky(acc[nj][0] + bv.x), wv.x, ss);
    ss = fmaf(lky(acc[nj][1] + bv.y), wv.y, ss);
    ss = fmaf(lky(acc[nj][2] + bv.z), wv.z, ss);
    ss = fmaf(lky(acc[nj][3] + bv.w), wv.w, ss);
  }
  ss += __shfl_xor(ss, 16);
  ss += __shfl_xor(ss, 32);          // all lanes now hold row-sum over wave's 64 n
  if (lane < 16) red[wid * 16 + lane] = ss;
  __syncthreads();
  if (t < 32) {
    const int mgq = t >> 4, ml = t & 15;
    const int gm = m0 + mgq * 16 + ml;
    const float val = red[mgq * 16 + ml] + red[(mgq + 2) * 16 + ml]
                    + rough[gm] + bout[0];
    const int gb = gm / N_ANTS, ga = gm - gb * N_ANTS;
    out[(size_t)gb * (N_ANTS + 1) + 1 + ga] = val;
  }
  if (t == 0) {   // EPSILON dummy column (duplicate same-value writes benign)
    for (int g = m0 / N_ANTS; g <= (m0 + 31) / N_ANTS; ++g)
      out[(size_t)g * (N_ANTS + 1)] = EPS_VAL;
  }
}

// ---- fallback (exact f32, used only if workspace too small) -----------------
__global__ void k_eps(float* __restrict__ out) {
  out[(size_t)threadIdx.x * (N_ANTS + 1)] = EPS_VAL;
}

__global__ __launch_bounds__(128) void k_fb(const float* __restrict__ all_m,
                                            const float* __restrict__ men,
                                            const float* __restrict__ pw,
                                            const int*   __restrict__ topi,
                                            const float* __restrict__ rough,
                                            const float* __restrict__ w1,
                                            const float* __restrict__ b1,
                                            const float* __restrict__ wout,
                                            const float* __restrict__ bout,
                                            float* __restrict__ out) {
  __shared__ float xs[IN_F];
  __shared__ float hred[HID];
  const int pair = blockIdx.x;
  const int t = threadIdx.x;
  const int bb = pair / N_ANTS;
  const int idx = topi[pair];
  const float* pA = men + (size_t)bb * EMB;
  const float* pB = all_m + (size_t)idx * EMB;
  for (int k = t; k < EMB; k += 128) {
    float a = pA[k], b = pB[k];
    xs[k] = a; xs[EMB + k] = b; xs[2 * EMB + k] = a * b;
  }
  if (t < PW_EMB) xs[3 * EMB + t] = pw[(size_t)pair * PW_EMB + t];
  __syncthreads();
  float acc = 0.f;
  for (int k = 0; k < IN_F; ++k) acc = fmaf(xs[k], w1[(size_t)k * HID + t], acc);
  acc += b1[t];
  acc = acc > 0.f ? acc : SLOPE * acc;
  hred[t] = acc * wout[t];
  __syncthreads();
  for (int off = 64; off > 0; off >>= 1) {
    if (t < off) hred[t] += hred[t + off];
    __syncthreads();
  }
  if (t == 0)
    out[(size_t)bb * (N_ANTS + 1) + 1 + (pair - bb * N_ANTS)] = rough[pair] + hred[0] + bout[0];
}

extern "C" void kernel_launch(void* const* d_in, const int* in_sizes, int n_in,
                              void* d_out, int out_size, void* d_ws, size_t ws_size,
                              hipStream_t stream) {
  const float* all_m = (const float*)d_in[0];
  const float* men   = (const float*)d_in[1];
  const float* pw    = (const float*)d_in[2];
  const int*   topi  = (const int*)  d_in[3];
  const float* rough = (const float*)d_in[4];
  const float* w1    = (const float*)d_in[5];
  const float* b1    = (const float*)d_in[6];
  const float* wout  = (const float*)d_in[7];
  const float* bout  = (const float*)d_in[8];
  float* out = (float*)d_out;

  const size_t W1F_BYTES = (size_t)HID * IN_F * sizeof(unsigned short);   // 802816

  if (ws_size >= W1F_BYTES) {
    unsigned short* w1f = (unsigned short*)d_ws;
    k_convert<<<CONV_BLK, 256, 0, stream>>>(w1, w1f);
    k_main<<<MAIN_BLK, 256, 0, stream>>>(all_m, men, pw, topi, rough, w1f,
                                         b1, wout, bout, out);
  } else {
    k_eps<<<1, BATCH, 0, stream>>>(out);
    k_fb<<<M_TOT, 128, 0, stream>>>(all_m, men, pw, topi, rough, w1, b1, wout, bout, out);
  }
}

// Round 9
// 54.298 us; speedup vs baseline: 1.7903x; 1.7903x over previous
//
#include <hip/hip_runtime.h>

#define N_MENT   10000
#define BATCH    512
#define N_ANTS   50
#define EMB      1024
#define PW_EMB   64
#define IN_F     3136       // 3*EMB + PW_EMB
#define HID      128
#define M_TOT    (BATCH * N_ANTS)   // 25600
#define EPS_VAL  1e-7f
#define SLOPE    0.01f

#define NKT      98         // IN_F/32 k-tiles, permuted: chunk c -> [a,a,b,b,s,s], then pw,pw
#define CONV_BLK 196        // 8 tn * 98 tk * 64 lanes / 256
#define MAIN_BLK (M_TOT / 32)   // 800

using f32x4 = __attribute__((ext_vector_type(4))) float;
using s16x8 = __attribute__((ext_vector_type(8))) short;
using u16x4 = __attribute__((ext_vector_type(4))) unsigned short;
using u16x8 = __attribute__((ext_vector_type(8))) unsigned short;

__device__ __forceinline__ unsigned short f2bf(float f) {
  unsigned u = __builtin_bit_cast(unsigned, f);
  u += 0x7FFFu + ((u >> 16) & 1u);   // RNE
  return (unsigned short)(u >> 16);
}

// pack 4 f32 -> 4 bf16 (RNE) via v_cvt_pk_bf16_f32 (bit-equal to f2bf; verified R4-R8)
__device__ __forceinline__ u16x4 pack4(float4 v) {
  union { u16x4 o; unsigned u[2]; } r;
  asm("v_cvt_pk_bf16_f32 %0, %1, %2" : "=v"(r.u[0]) : "v"(v.x), "v"(v.y));
  asm("v_cvt_pk_bf16_f32 %0, %1, %2" : "=v"(r.u[1]) : "v"(v.z), "v"(v.w));
  return r.o;
}

__device__ __forceinline__ float4 fmul4(float4 a, float4 b) {
  return make_float4(a.x * b.x, a.y * b.y, a.z * b.z, a.w * b.w);
}

// permuted k-tile -> original W1 row base.
//   tk in [0,96): chunk c = tk/6, r = tk%6; region = r>>1 (0=a,1=b,2=sim), ks = r&1
//                 orig = region*1024 + c*64 + ks*32
//   tk 96,97   -> pw rows 3072 + (tk-96)*32
__device__ __forceinline__ int tile_orig_k(int tk) {
  if (tk >= 96) return 3072 + (tk - 96) * 32;
  const int c = tk / 6, r = tk % 6;
  return (r >> 1) * 1024 + c * 64 + (r & 1) * 32;
}

// ---- kernel 0: W1 [3136][128] f32 -> w1f in MFMA B-fragment-linear order ----
// w1f element index = ((tn*NKT + tk)*64 + lane)*8 + j
//   lane = ln + lg*16 holds W1[k = orig_k(tk) + lg*8 + j][n = tn*16 + ln]
__global__ __launch_bounds__(256) void k_convert(const float* __restrict__ w1,
                                                 unsigned short* __restrict__ w1f) {
  const int id   = blockIdx.x * 256 + threadIdx.x;   // 0..50175
  const int lane = id & 63;
  const int tile = id >> 6;                          // 0..783 = tn*98 + tk
  const int tk   = tile % NKT, tn = tile / NKT;
  const int n    = tn * 16 + (lane & 15);
  const int k    = tile_orig_k(tk) + (lane >> 4) * 8;
  u16x8 o;
  #pragma unroll
  for (int j = 0; j < 8; ++j) o[j] = f2bf(w1[(size_t)(k + j) * HID + n]);
  *(u16x8*)(w1f + (size_t)id * 8) = o;
}

// ---- kernel 1: fused GEMM, K=3136 (a | b | a*b | pw), BM=32, 8 waves --------
// R7 schedule (one barrier/chunk, double-buffered LDS X tiles, W-frags
// register-loaded before the barrier) at 2x the waves/CU: 512 threads,
// each wave owns ONE 16-col n-tile (8 waves cover HID=128).
__global__ __launch_bounds__(512) void k_main(
    const float* __restrict__ all_m, const float* __restrict__ men,
    const float* __restrict__ pw, const int* __restrict__ topi,
    const float* __restrict__ rough, const unsigned short* __restrict__ w1f,
    const float* __restrict__ b1, const float* __restrict__ wout,
    const float* __restrict__ bout, float* __restrict__ out) {
  __shared__ __align__(16) unsigned short Xs[2][3][32 * 72];
  __shared__ float red[8 * 32];

  const int t  = threadIdx.x;
  const int m0 = blockIdx.x * 32;

  // staging identity: row sr (0..31), 4-float col group sq (0..15)
  const int sr = t >> 4, sq = t & 15;
  const int m  = m0 + sr;
  const int bb = m / N_ANTS;
  const int bidx = topi[m];
  const float* pA = men   + (size_t)bb   * EMB    + sq * 4;
  const float* pB = all_m + (size_t)bidx * EMB    + sq * 4;
  const float* pP = pw    + (size_t)m    * PW_EMB + sq * 4;

  // compute identity: wave wid (0..7) owns n-tile wid (cols wid*16 + ln)
  const int lane = t & 63, wid = t >> 6;
  const int ln = lane & 15, lg = lane >> 4;
  const unsigned short* wf = w1f + (size_t)wid * NKT * 512 + lane * 8;

  f32x4 acc[2] = {};   // acc[0]: rows m0+0..15, acc[1]: rows m0+16..31

  float4 av = ((const float4*)pA)[0];
  float4 bv = ((const float4*)pB)[0];

  int buf = 0;
  for (int c = 0; c < 16; ++c) {
    // stage three tiles: 0 = a, 1 = b, 2 = a*b   (8B per thread per tile)
    *(u16x4*)&Xs[buf][0][sr * 72 + sq * 4] = pack4(av);
    *(u16x4*)&Xs[buf][1][sr * 72 + sq * 4] = pack4(bv);
    *(u16x4*)&Xs[buf][2][sr * 72 + sq * 4] = pack4(fmul4(av, bv));

    // depth-1 prefetch of next chunk's rows (pw at the end)
    if (c < 15) {
      av = ((const float4*)(pA + (c + 1) * 64))[0];
      bv = ((const float4*)(pB + (c + 1) * 64))[0];
    } else {
      av = ((const float4*)pP)[0];
    }

    // this chunk's 6 W-fragments into registers before the barrier
    s16x8 wr[6];
    #pragma unroll
    for (int j = 0; j < 6; ++j)
      wr[j] = *(const s16x8*)(wf + (size_t)(c * 6 + j) * 512);

    __syncthreads();
    #pragma unroll
    for (int j = 0; j < 6; ++j) {
      const int reg = j >> 1, ks = j & 1;
      s16x8 x0 = *(const s16x8*)&Xs[buf][reg][ln * 72        + ks * 32 + lg * 8];
      s16x8 x1 = *(const s16x8*)&Xs[buf][reg][(16 + ln) * 72 + ks * 32 + lg * 8];
      acc[0] = __builtin_amdgcn_mfma_f32_16x16x32_bf16(x0, wr[j], acc[0], 0, 0, 0);
      acc[1] = __builtin_amdgcn_mfma_f32_16x16x32_bf16(x1, wr[j], acc[1], 0, 0, 0);
    }
    buf ^= 1;
  }

  // pw chunk: av holds pw values; k-tiles 96,97
  {
    *(u16x4*)&Xs[buf][0][sr * 72 + sq * 4] = pack4(av);
    s16x8 wr[2];
    #pragma unroll
    for (int ks = 0; ks < 2; ++ks)
      wr[ks] = *(const s16x8*)(wf + (size_t)(96 + ks) * 512);
    __syncthreads();
    #pragma unroll
    for (int ks = 0; ks < 2; ++ks) {
      s16x8 x0 = *(const s16x8*)&Xs[buf][0][ln * 72        + ks * 32 + lg * 8];
      s16x8 x1 = *(const s16x8*)&Xs[buf][0][(16 + ln) * 72 + ks * 32 + lg * 8];
      acc[0] = __builtin_amdgcn_mfma_f32_16x16x32_bf16(x0, wr[ks], acc[0], 0, 0, 0);
      acc[1] = __builtin_amdgcn_mfma_f32_16x16x32_bf16(x1, wr[ks], acc[1], 0, 0, 0);
    }
  }

  // epilogue: lane holds C[m = mf*16 + lg*4 + e][n = wid*16 + ln]
  const int n0 = wid * 16 + ln;
  const float bias = b1[n0], w_o = wout[n0];
  #pragma unroll
  for (int mf = 0; mf < 2; ++mf)
    #pragma unroll
    for (int e = 0; e < 4; ++e) {
      float h = acc[mf][e] + bias;
      h = h > 0.f ? h : SLOPE * h;
      float ss = h * w_o;
      ss += __shfl_xor(ss, 1);
      ss += __shfl_xor(ss, 2);
      ss += __shfl_xor(ss, 4);
      ss += __shfl_xor(ss, 8);
      if (ln == 0) red[wid * 32 + mf * 16 + lg * 4 + e] = ss;
    }
  __syncthreads();
  if (t < 32) {
    const int gm = m0 + t;
    float v = red[t];
    #pragma unroll
    for (int w = 1; w < 8; ++w) v += red[w * 32 + t];
    const int gb = gm / N_ANTS;
    const int ga = gm - gb * N_ANTS;
    out[(size_t)gb * (N_ANTS + 1) + 1 + ga] = rough[gm] + v + bout[0];
  }
  if (t == 0) {   // EPSILON dummy column (duplicate same-value writes benign)
    for (int g = m0 / N_ANTS; g <= (m0 + 31) / N_ANTS; ++g)
      out[(size_t)g * (N_ANTS + 1)] = EPS_VAL;
  }
}

// ---- fallback (exact f32, used only if workspace too small) -----------------
__global__ void k_eps(float* __restrict__ out) {
  out[(size_t)threadIdx.x * (N_ANTS + 1)] = EPS_VAL;
}

__global__ __launch_bounds__(128) void k_fb(const float* __restrict__ all_m,
                                            const float* __restrict__ men,
                                            const float* __restrict__ pw,
                                            const int*   __restrict__ topi,
                                            const float* __restrict__ rough,
                                            const float* __restrict__ w1,
                                            const float* __restrict__ b1,
                                            const float* __restrict__ wout,
                                            const float* __restrict__ bout,
                                            float* __restrict__ out) {
  __shared__ float xs[IN_F];
  __shared__ float hred[HID];
  const int pair = blockIdx.x;
  const int t = threadIdx.x;
  const int bb = pair / N_ANTS;
  const int idx = topi[pair];
  const float* pA = men + (size_t)bb * EMB;
  const float* pB = all_m + (size_t)idx * EMB;
  for (int k = t; k < EMB; k += 128) {
    float a = pA[k], b = pB[k];
    xs[k] = a; xs[EMB + k] = b; xs[2 * EMB + k] = a * b;
  }
  if (t < PW_EMB) xs[3 * EMB + t] = pw[(size_t)pair * PW_EMB + t];
  __syncthreads();
  float acc = 0.f;
  for (int k = 0; k < IN_F; ++k) acc = fmaf(xs[k], w1[(size_t)k * HID + t], acc);
  acc += b1[t];
  acc = acc > 0.f ? acc : SLOPE * acc;
  hred[t] = acc * wout[t];
  __syncthreads();
  for (int off = 64; off > 0; off >>= 1) {
    if (t < off) hred[t] += hred[t + off];
    __syncthreads();
  }
  if (t == 0)
    out[(size_t)bb * (N_ANTS + 1) + 1 + (pair - bb * N_ANTS)] = rough[pair] + hred[0] + bout[0];
}

extern "C" void kernel_launch(void* const* d_in, const int* in_sizes, int n_in,
                              void* d_out, int out_size, void* d_ws, size_t ws_size,
                              hipStream_t stream) {
  const float* all_m = (const float*)d_in[0];
  const float* men   = (const float*)d_in[1];
  const float* pw    = (const float*)d_in[2];
  const int*   topi  = (const int*)  d_in[3];
  const float* rough = (const float*)d_in[4];
  const float* w1    = (const float*)d_in[5];
  const float* b1    = (const float*)d_in[6];
  const float* wout  = (const float*)d_in[7];
  const float* bout  = (const float*)d_in[8];
  float* out = (float*)d_out;

  const size_t W1F_BYTES = (size_t)HID * IN_F * sizeof(unsigned short);   // 802816

  if (ws_size >= W1F_BYTES) {
    unsigned short* w1f = (unsigned short*)d_ws;
    k_convert<<<CONV_BLK, 256, 0, stream>>>(w1, w1f);
    k_main<<<MAIN_BLK, 512, 0, stream>>>(all_m, men, pw, topi, rough, w1f,
                                         b1, wout, bout, out);
  } else {
    k_eps<<<1, BATCH, 0, stream>>>(out);
    k_fb<<<M_TOT, 128, 0, stream>>>(all_m, men, pw, topi, rough, w1, b1, wout, bout, out);
  }
}

// Round 10
// 49.217 us; speedup vs baseline: 1.9751x; 1.1032x over previous
//
#include <hip/hip_runtime.h>

#define N_MENT   10000
#define BATCH    512
#define N_ANTS   50
#define EMB      1024
#define PW_EMB   64
#define IN_F     3136       // 3*EMB + PW_EMB
#define HID      128
#define M_TOT    (BATCH * N_ANTS)   // 25600
#define EPS_VAL  1e-7f
#define SLOPE    0.01f

#define NKT      98         // IN_F/32 k-tiles, permuted: chunk c -> [a,a,b,b,s,s], then pw,pw
#define CONV_BLK 196        // 8 tn * 98 tk * 64 lanes / 256
#define MAIN_BLK (M_TOT / 64)   // 400  (all resident: 2 blocks/CU * 256 = 512 slots)

using f32x4 = __attribute__((ext_vector_type(4))) float;
using s16x8 = __attribute__((ext_vector_type(8))) short;
using u16x4 = __attribute__((ext_vector_type(4))) unsigned short;
using u16x8 = __attribute__((ext_vector_type(8))) unsigned short;

__device__ __forceinline__ unsigned short f2bf(float f) {
  unsigned u = __builtin_bit_cast(unsigned, f);
  u += 0x7FFFu + ((u >> 16) & 1u);   // RNE
  return (unsigned short)(u >> 16);
}

// pack 4 f32 -> 4 bf16 (RNE) via v_cvt_pk_bf16_f32 (bit-equal to f2bf; verified R4-R9)
__device__ __forceinline__ u16x4 pack4(float4 v) {
  union { u16x4 o; unsigned u[2]; } r;
  asm("v_cvt_pk_bf16_f32 %0, %1, %2" : "=v"(r.u[0]) : "v"(v.x), "v"(v.y));
  asm("v_cvt_pk_bf16_f32 %0, %1, %2" : "=v"(r.u[1]) : "v"(v.z), "v"(v.w));
  return r.o;
}

__device__ __forceinline__ float4 fmul4(float4 a, float4 b) {
  return make_float4(a.x * b.x, a.y * b.y, a.z * b.z, a.w * b.w);
}

// permuted k-tile -> original W1 row base.
//   tk in [0,96): chunk c = tk/6, r = tk%6; region = r>>1 (0=a,1=b,2=sim), ks = r&1
//                 orig = region*1024 + c*64 + ks*32
//   tk 96,97   -> pw rows 3072 + (tk-96)*32
__device__ __forceinline__ int tile_orig_k(int tk) {
  if (tk >= 96) return 3072 + (tk - 96) * 32;
  const int c = tk / 6, r = tk % 6;
  return (r >> 1) * 1024 + c * 64 + (r & 1) * 32;
}

// ---- kernel 0: W1 [3136][128] f32 -> w1f in MFMA B-fragment-linear order ----
// w1f element index = ((tn*NKT + tk)*64 + lane)*8 + j
//   lane = ln + lg*16 holds W1[k = orig_k(tk) + lg*8 + j][n = tn*16 + ln]
__global__ __launch_bounds__(256) void k_convert(const float* __restrict__ w1,
                                                 unsigned short* __restrict__ w1f) {
  const int id   = blockIdx.x * 256 + threadIdx.x;   // 0..50175
  const int lane = id & 63;
  const int tile = id >> 6;                          // 0..783 = tn*98 + tk
  const int tk   = tile % NKT, tn = tile / NKT;
  const int n    = tn * 16 + (lane & 15);
  const int k    = tile_orig_k(tk) + (lane >> 4) * 8;
  u16x8 o;
  #pragma unroll
  for (int j = 0; j < 8; ++j) o[j] = f2bf(w1[(size_t)(k + j) * HID + n]);
  *(u16x8*)(w1f + (size_t)id * 8) = o;
}

// ---- kernel 1: fused GEMM, K=3136 (a | b | a*b | pw), BM=64, 8 waves --------
// Wave wid owns n-tile wid (cols wid*16..+15) for ALL 4 m-tiles -> each W
// fragment stream read once per block (W L2 traffic halved vs BM=32).
// One barrier per 64-k chunk; W-frags prefetched one chunk ahead (R3 pattern).
__global__ __launch_bounds__(512) void k_main(
    const float* __restrict__ all_m, const float* __restrict__ men,
    const float* __restrict__ pw, const int* __restrict__ topi,
    const float* __restrict__ rough, const unsigned short* __restrict__ w1f,
    const float* __restrict__ b1, const float* __restrict__ wout,
    const float* __restrict__ bout, float* __restrict__ out) {
  __shared__ __align__(16) unsigned short Xs[2][3][64 * 72];
  __shared__ float red[8][64];

  const int t  = threadIdx.x;
  const int m0 = blockIdx.x * 64;

  // staging identity: row sr (0..63), 8-float col group sq (0..7)
  const int sr = t >> 3, sq = t & 7;
  const int m  = m0 + sr;
  const int bb = m / N_ANTS;
  const int bidx = topi[m];
  const float* pA = men   + (size_t)bb   * EMB    + sq * 8;
  const float* pB = all_m + (size_t)bidx * EMB    + sq * 8;
  const float* pP = pw    + (size_t)m    * PW_EMB + sq * 8;

  // compute identity: wave wid (0..7) owns n-tile wid
  const int lane = t & 63, wid = t >> 6;
  const int ln = lane & 15, lg = lane >> 4;
  const unsigned short* wf = w1f + (size_t)wid * NKT * 512 + lane * 8;

  f32x4 acc[4] = {};   // acc[mt]: rows m0 + mt*16 .. +15

  float4 av0 = ((const float4*)pA)[0], av1 = ((const float4*)pA)[1];
  float4 bv0 = ((const float4*)pB)[0], bv1 = ((const float4*)pB)[1];

  // W fragments for chunk 0 (k-tiles 0..5)
  s16x8 wcur[6], wnext[6];
  #pragma unroll
  for (int j = 0; j < 6; ++j)
    wcur[j] = *(const s16x8*)(wf + (size_t)j * 512);

  int buf = 0;
  for (int c = 0; c < 16; ++c) {
    // stage three tiles: 0 = a, 1 = b, 2 = a*b   (16B per thread per tile)
    *(u16x4*)&Xs[buf][0][sr * 72 + sq * 8]     = pack4(av0);
    *(u16x4*)&Xs[buf][0][sr * 72 + sq * 8 + 4] = pack4(av1);
    *(u16x4*)&Xs[buf][1][sr * 72 + sq * 8]     = pack4(bv0);
    *(u16x4*)&Xs[buf][1][sr * 72 + sq * 8 + 4] = pack4(bv1);
    *(u16x4*)&Xs[buf][2][sr * 72 + sq * 8]     = pack4(fmul4(av0, bv0));
    *(u16x4*)&Xs[buf][2][sr * 72 + sq * 8 + 4] = pack4(fmul4(av1, bv1));

    // depth-1 prefetch of next chunk's rows (pw at the end; bv unused then)
    if (c < 15) {
      const float* qA = pA + (c + 1) * 64;
      const float* qB = pB + (c + 1) * 64;
      av0 = ((const float4*)qA)[0]; av1 = ((const float4*)qA)[1];
      bv0 = ((const float4*)qB)[0]; bv1 = ((const float4*)qB)[1];
    } else {
      av0 = ((const float4*)pP)[0]; av1 = ((const float4*)pP)[1];
    }

    // depth-1 prefetch of NEXT chunk's W fragments (R3-proven pattern):
    // issued before this barrier, consumed after the next -> full-chunk cover.
    #pragma unroll
    for (int j = 0; j < 6; ++j) {
      const int tkn = (c < 15) ? (c + 1) * 6 + j : (j < 2 ? 96 + j : 97);
      wnext[j] = *(const s16x8*)(wf + (size_t)tkn * 512);
    }

    __syncthreads();
    #pragma unroll
    for (int j = 0; j < 6; ++j) {
      const int reg = j >> 1, ks = j & 1;
      #pragma unroll
      for (int mt = 0; mt < 4; ++mt) {
        s16x8 x = *(const s16x8*)&Xs[buf][reg][(mt * 16 + ln) * 72 + ks * 32 + lg * 8];
        acc[mt] = __builtin_amdgcn_mfma_f32_16x16x32_bf16(x, wcur[j], acc[mt], 0, 0, 0);
      }
    }
    #pragma unroll
    for (int j = 0; j < 6; ++j) wcur[j] = wnext[j];
    buf ^= 1;
  }

  // pw chunk: av0/av1 hold pw values; k-tiles 96,97 are wcur[0],wcur[1]
  {
    *(u16x4*)&Xs[buf][0][sr * 72 + sq * 8]     = pack4(av0);
    *(u16x4*)&Xs[buf][0][sr * 72 + sq * 8 + 4] = pack4(av1);
    __syncthreads();
    #pragma unroll
    for (int ks = 0; ks < 2; ++ks)
      #pragma unroll
      for (int mt = 0; mt < 4; ++mt) {
        s16x8 x = *(const s16x8*)&Xs[buf][0][(mt * 16 + ln) * 72 + ks * 32 + lg * 8];
        acc[mt] = __builtin_amdgcn_mfma_f32_16x16x32_bf16(x, wcur[ks], acc[mt], 0, 0, 0);
      }
  }

  // epilogue: lane holds C[m = mt*16 + lg*4 + e][n = wid*16 + ln]
  const int n0 = wid * 16 + ln;
  const float bias = b1[n0], w_o = wout[n0];
  #pragma unroll
  for (int mt = 0; mt < 4; ++mt)
    #pragma unroll
    for (int e = 0; e < 4; ++e) {
      float h = acc[mt][e] + bias;
      h = h > 0.f ? h : SLOPE * h;
      float ss = h * w_o;
      ss += __shfl_xor(ss, 1);
      ss += __shfl_xor(ss, 2);
      ss += __shfl_xor(ss, 4);
      ss += __shfl_xor(ss, 8);
      if (ln == 0) red[wid][mt * 16 + lg * 4 + e] = ss;
    }
  __syncthreads();
  if (t < 64) {
    const int gm = m0 + t;
    float v = red[0][t];
    #pragma unroll
    for (int w = 1; w < 8; ++w) v += red[w][t];
    const int gb = gm / N_ANTS;
    const int ga = gm - gb * N_ANTS;
    out[(size_t)gb * (N_ANTS + 1) + 1 + ga] = rough[gm] + v + bout[0];
  }
  if (t == 0) {   // EPSILON dummy column (duplicate same-value writes benign)
    for (int g = m0 / N_ANTS; g <= (m0 + 63) / N_ANTS; ++g)
      out[(size_t)g * (N_ANTS + 1)] = EPS_VAL;
  }
}

// ---- fallback (exact f32, used only if workspace too small) -----------------
__global__ void k_eps(float* __restrict__ out) {
  out[(size_t)threadIdx.x * (N_ANTS + 1)] = EPS_VAL;
}

__global__ __launch_bounds__(128) void k_fb(const float* __restrict__ all_m,
                                            const float* __restrict__ men,
                                            const float* __restrict__ pw,
                                            const int*   __restrict__ topi,
                                            const float* __restrict__ rough,
                                            const float* __restrict__ w1,
                                            const float* __restrict__ b1,
                                            const float* __restrict__ wout,
                                            const float* __restrict__ bout,
                                            float* __restrict__ out) {
  __shared__ float xs[IN_F];
  __shared__ float hred[HID];
  const int pair = blockIdx.x;
  const int t = threadIdx.x;
  const int bb = pair / N_ANTS;
  const int idx = topi[pair];
  const float* pA = men + (size_t)bb * EMB;
  const float* pB = all_m + (size_t)idx * EMB;
  for (int k = t; k < EMB; k += 128) {
    float a = pA[k], b = pB[k];
    xs[k] = a; xs[EMB + k] = b; xs[2 * EMB + k] = a * b;
  }
  if (t < PW_EMB) xs[3 * EMB + t] = pw[(size_t)pair * PW_EMB + t];
  __syncthreads();
  float acc = 0.f;
  for (int k = 0; k < IN_F; ++k) acc = fmaf(xs[k], w1[(size_t)k * HID + t], acc);
  acc += b1[t];
  acc = acc > 0.f ? acc : SLOPE * acc;
  hred[t] = acc * wout[t];
  __syncthreads();
  for (int off = 64; off > 0; off >>= 1) {
    if (t < off) hred[t] += hred[t + off];
    __syncthreads();
  }
  if (t == 0)
    out[(size_t)bb * (N_ANTS + 1) + 1 + (pair - bb * N_ANTS)] = rough[pair] + hred[0] + bout[0];
}

extern "C" void kernel_launch(void* const* d_in, const int* in_sizes, int n_in,
                              void* d_out, int out_size, void* d_ws, size_t ws_size,
                              hipStream_t stream) {
  const float* all_m = (const float*)d_in[0];
  const float* men   = (const float*)d_in[1];
  const float* pw    = (const float*)d_in[2];
  const int*   topi  = (const int*)  d_in[3];
  const float* rough = (const float*)d_in[4];
  const float* w1    = (const float*)d_in[5];
  const float* b1    = (const float*)d_in[6];
  const float* wout  = (const float*)d_in[7];
  const float* bout  = (const float*)d_in[8];
  float* out = (float*)d_out;

  const size_t W1F_BYTES = (size_t)HID * IN_F * sizeof(unsigned short);   // 802816

  if (ws_size >= W1F_BYTES) {
    unsigned short* w1f = (unsigned short*)d_ws;
    k_convert<<<CONV_BLK, 256, 0, stream>>>(w1, w1f);
    k_main<<<MAIN_BLK, 512, 0, stream>>>(all_m, men, pw, topi, rough, w1f,
                                         b1, wout, bout, out);
  } else {
    k_eps<<<1, BATCH, 0, stream>>>(out);
    k_fb<<<M_TOT, 128, 0, stream>>>(all_m, men, pw, topi, rough, w1, b1, wout, bout, out);
  }
}